// Round 2
// baseline (226.274 us; speedup 1.0000x reference)
//
#include <hip/hip_runtime.h>

#define IMG 512
#define OUTCH ((size_t)48 * 512 * 512)   // floats per output tensor
#define NTHREADS (48 * 64 * 128)         // one thread per 4x8 half-block: 393216

// Orthonormal 8-point DCT-II matrix D[k][t]
__device__ constexpr float Dm[8][8] = {
  { 0.3535533905932738f, 0.3535533905932738f, 0.3535533905932738f, 0.3535533905932738f,
    0.3535533905932738f, 0.3535533905932738f, 0.3535533905932738f, 0.3535533905932738f},
  { 0.4903926402016152f, 0.4157348061512726f, 0.2777851165098011f, 0.0975451610080642f,
   -0.0975451610080642f,-0.2777851165098011f,-0.4157348061512726f,-0.4903926402016152f},
  { 0.4619397662556434f, 0.1913417161825449f,-0.1913417161825449f,-0.4619397662556434f,
   -0.4619397662556434f,-0.1913417161825449f, 0.1913417161825449f, 0.4619397662556434f},
  { 0.4157348061512726f,-0.0975451610080642f,-0.4903926402016152f,-0.2777851165098011f,
    0.2777851165098011f, 0.4903926402016152f, 0.0975451610080642f,-0.4157348061512726f},
  { 0.3535533905932738f,-0.3535533905932738f,-0.3535533905932738f, 0.3535533905932738f,
    0.3535533905932738f,-0.3535533905932738f,-0.3535533905932738f, 0.3535533905932738f},
  { 0.2777851165098011f,-0.4903926402016152f, 0.0975451610080642f, 0.4157348061512726f,
   -0.4157348061512726f,-0.0975451610080642f, 0.4903926402016152f,-0.2777851165098011f},
  { 0.1913417161825449f,-0.4619397662556434f, 0.4619397662556434f,-0.1913417161825449f,
   -0.1913417161825449f, 0.4619397662556434f,-0.4619397662556434f, 0.1913417161825449f},
  { 0.0975451610080642f,-0.2777851165098011f, 0.4157348061512726f,-0.4903926402016152f,
    0.4903926402016152f,-0.4157348061512726f, 0.2777851165098011f,-0.0975451610080642f},
};

// 8x8 zigzag order (validated by the passing round-1 kernel)
__device__ constexpr int ZZ[8][8] = {
  {  0,  1,  5,  6, 14, 15, 27, 28},
  {  2,  4,  7, 13, 16, 26, 29, 42},
  {  3,  8, 12, 17, 25, 30, 41, 43},
  {  9, 11, 18, 24, 31, 40, 44, 53},
  { 10, 19, 23, 32, 39, 45, 52, 54},
  { 20, 22, 33, 38, 46, 51, 55, 60},
  { 21, 34, 37, 47, 50, 56, 59, 61},
  { 35, 36, 48, 49, 57, 58, 62, 63},
};

// Forward horizontal DCT for a lane owning in-block cols [L0, L0+4).
// T = my 4 columns (vertically transformed), To = partner's 4 columns.
// C[k][j] = coeff at vertical freq k, horizontal freq L0+j.
template <int L0>
__device__ __forceinline__ void horiz_fwd(const float (&T)[8][4],
                                          const float (&To)[8][4],
                                          float (&C)[8][4]) {
#pragma unroll
  for (int k = 0; k < 8; ++k) {
    float F[8];
#pragma unroll
    for (int j = 0; j < 4; ++j) {
      F[(L0 == 0) ? j     : 4 + j] = T[k][j];   // my cols sit at n = L0+j
      F[(L0 == 0) ? 4 + j : j    ] = To[k][j];  // partner covers the other half
    }
#pragma unroll
    for (int j = 0; j < 4; ++j) {
      float acc = 0.0f;
#pragma unroll
      for (int n = 0; n < 8; ++n) acc += F[n] * Dm[L0 + j][n];
      C[k][j] = acc;
    }
  }
}

// Masked vertical IDCT stage: U[m][j] = sum_k Dm[k][m] * C[k][j] for
// coeffs whose zigzag index at (k, L0+j) lies in [LOB, HIB). Compile-time mask.
template <int L0, int LOB, int HIB>
__device__ __forceinline__ void stage1(const float (&C)[8][4], float (&U)[8][4]) {
#pragma unroll
  for (int m = 0; m < 8; ++m)
#pragma unroll
    for (int j = 0; j < 4; ++j) {
      float acc = 0.0f;
#pragma unroll
      for (int k = 0; k < 8; ++k)
        if (ZZ[k][L0 + j] >= LOB && ZZ[k][L0 + j] < HIB) acc += Dm[k][m] * C[k][j];
      U[m][j] = acc;
    }
}

// Horizontal IDCT stage: V[m][j] = sp[m][n=L0+j] = sum_l Ufull[l]*Dm[l][L0+j]
template <int L0>
__device__ __forceinline__ void stage2(const float (&U)[8][4],
                                       const float (&Uo)[8][4],
                                       float (&V)[8][4]) {
#pragma unroll
  for (int m = 0; m < 8; ++m) {
    float F[8];
#pragma unroll
    for (int j = 0; j < 4; ++j) {
      F[(L0 == 0) ? j     : 4 + j] = U[m][j];   // my freqs are l = L0+j
      F[(L0 == 0) ? 4 + j : j    ] = Uo[m][j];  // partner holds the other freqs
    }
#pragma unroll
    for (int j = 0; j < 4; ++j) {
      float acc = 0.0f;
#pragma unroll
      for (int l = 0; l < 8; ++l) acc += F[l] * Dm[l][L0 + j];
      V[m][j] = acc;
    }
  }
}

__global__ __launch_bounds__(256, 3) void dct_decomp_kernel(
    const float* __restrict__ x, const float* __restrict__ band_scale,
    float* __restrict__ out) {
  int tid = blockIdx.x * 256 + threadIdx.x;
  int pc  = tid & 127;          // 4-wide patch column (0..127); lane pairs share a block
  int bh  = (tid >> 7) & 63;    // block row
  int img = tid >> 13;          // b*3 + c
  bool odd = (pc & 1) != 0;     // which half of the 8x8 block this lane owns

  size_t base = ((size_t)img * IMG + (size_t)bh * 8) * IMG + (size_t)pc * 4;
  const float* src = x + base;

  // Perfectly coalesced loads: 16B/lane, 1KB contiguous per instruction.
  float X[8][4];
#pragma unroll
  for (int r = 0; r < 8; ++r) {
    float4 v = *(const float4*)(src + (size_t)r * IMG);
    X[r][0] = v.x; X[r][1] = v.y; X[r][2] = v.z; X[r][3] = v.w;
  }

  // Vertical forward DCT (per-lane, per-column)
  float T[8][4];
#pragma unroll
  for (int k = 0; k < 8; ++k)
#pragma unroll
    for (int j = 0; j < 4; ++j) {
      float acc = 0.0f;
#pragma unroll
      for (int r = 0; r < 8; ++r) acc += Dm[k][r] * X[r][j];
      T[k][j] = acc;
    }

  // Exchange columns with the partner lane (other half of the block)
  float To[8][4];
#pragma unroll
  for (int k = 0; k < 8; ++k)
#pragma unroll
    for (int j = 0; j < 4; ++j) To[k][j] = __shfl_xor(T[k][j], 1);

  float C[8][4];
  if (!odd) horiz_fwd<0>(T, To, C); else horiz_fwd<4>(T, To, C);

  float s0 = band_scale[0];
  float s1 = band_scale[1];
  float s2 = band_scale[2];

  float U[8][4], Uo[8][4], V[8][4];

  // ---- low band: zigzag [0,21) ----
  if (!odd) stage1<0, 0, 21>(C, U); else stage1<4, 0, 21>(C, U);
#pragma unroll
  for (int m = 0; m < 8; ++m)
#pragma unroll
    for (int j = 0; j < 4; ++j) Uo[m][j] = __shfl_xor(U[m][j], 1);
  if (!odd) stage2<0>(U, Uo, V); else stage2<4>(U, Uo, V);
#pragma unroll
  for (int m = 0; m < 8; ++m) {
    float4 w = make_float4(V[m][0] * s0, V[m][1] * s0, V[m][2] * s0, V[m][3] * s0);
    *(float4*)(out + base + (size_t)m * IMG) = w;
#pragma unroll
    for (int j = 0; j < 4; ++j) X[m][j] -= V[m][j];  // accumulate residual
  }

  // ---- mid band: zigzag [21,42) ----
  if (!odd) stage1<0, 21, 42>(C, U); else stage1<4, 21, 42>(C, U);
#pragma unroll
  for (int m = 0; m < 8; ++m)
#pragma unroll
    for (int j = 0; j < 4; ++j) Uo[m][j] = __shfl_xor(U[m][j], 1);
  if (!odd) stage2<0>(U, Uo, V); else stage2<4>(U, Uo, V);
#pragma unroll
  for (int m = 0; m < 8; ++m) {
    float4 w = make_float4(V[m][0] * s1, V[m][1] * s1, V[m][2] * s1, V[m][3] * s1);
    *(float4*)(out + OUTCH + base + (size_t)m * IMG) = w;
#pragma unroll
    for (int j = 0; j < 4; ++j) X[m][j] -= V[m][j];
  }

  // ---- high band = residual (low+mid+high partition all 64 coeffs) ----
#pragma unroll
  for (int m = 0; m < 8; ++m) {
    float4 w = make_float4(X[m][0] * s2, X[m][1] * s2, X[m][2] * s2, X[m][3] * s2);
    *(float4*)(out + 2 * OUTCH + base + (size_t)m * IMG) = w;
  }
}

extern "C" void kernel_launch(void* const* d_in, const int* in_sizes, int n_in,
                              void* d_out, int out_size, void* d_ws, size_t ws_size,
                              hipStream_t stream) {
  const float* x          = (const float*)d_in[0];
  const float* band_scale = (const float*)d_in[1];
  float* out              = (float*)d_out;

  dim3 grid(NTHREADS / 256);  // 1536 workgroups
  dim3 block(256);
  dct_decomp_kernel<<<grid, block, 0, stream>>>(x, band_scale, out);
}